// Round 5
// baseline (545.843 us; speedup 1.0000x reference)
//
#include <hip/hip_runtime.h>

#define H    128
#define T    512
#define DX   4
#define BB   220
#define SAMP 10
#define NS   (BB*SAMP)
#define M    16       // sequences per block (transposed MFMA: 16 distinct B-cols)
#define NBLK 14       // ceil(220/16); last block has 4 pad seqs
#define NCH  8        // x chunks of 64 steps

typedef _Float16 half8 __attribute__((ext_vector_type(8)));
typedef float    f32x4 __attribute__((ext_vector_type(4)));

// workspace layout (fp32 elements)
#define WS_TEMB 0
#define WS_AEMB (WS_TEMB + BB*H)
#define WS_FEMB (WS_AEMB + BB*H)
#define WS_TA   (WS_FEMB + BB*H)
#define WS_TF   (WS_TA + NS*H)
#define WS_AN   (WS_TF + NS*H)
#define WS_FA   (WS_AN + NS*H)
#define WS_FLAGS (WS_FA + NS*H)   // 2 ints: [0]=floats-are-bf16, [1]=ints-are-int64

#define LOG2E  1.442695041f
#define LOG2E2 2.885390082f

__device__ static inline float bf2f(unsigned short u) {
  unsigned int i = ((unsigned int)u) << 16;
  return __builtin_bit_cast(float, i);
}
__device__ static inline unsigned short f2bf(float f) {
  unsigned int i = __builtin_bit_cast(unsigned int, f);
  i += 0x7fffu + ((i >> 16) & 1u);
  return (unsigned short)(i >> 16);
}
__device__ static inline float loadF(const void* p, size_t i, int isbf) {
  return isbf ? bf2f(((const unsigned short*)p)[i]) : ((const float*)p)[i];
}
__device__ static inline int loadI(const void* p, int i, int is64) {
  return is64 ? (int)((const unsigned int*)p)[2*(size_t)i] : ((const int*)p)[i];
}
__device__ static inline float frcp(float x) { return __builtin_amdgcn_rcpf(x); }
__device__ static inline float ex2(float x)  { return __builtin_amdgcn_exp2f(x); }
// args pre-scaled by log2e (sigm) / 2*log2e (tanh)
__device__ static inline float sigmY(float y)  { return frcp(1.f + ex2(-y)); }
__device__ static inline float tanhY(float y)  { return 1.f - 2.f*frcp(1.f + ex2(y)); }
__device__ static inline float scrub(float x) { return (x == x) ? x : 0.f; }
__device__ static inline int clampT(int v) { v = v - 1; if (v < 0) v = 0; if (v > T-1) v = T-1; return v; }

// Transposed formulation: gates^T[512][16] = Whh_scaled[512][128] @ h^T[128][16].
// A = weights (STATIC in VGPRs, loaded once). B = h^T (4 KB in LDS, ping-pong).
// Gate-rows interleaved [h-col][gate]: row r of row-tile rt -> h-col rt*4+(r>>2),
// gate r&3. D lane (quad,lo): rows quad*4+q, col lo  =>  cell (seq=lo,
// hcol=rt*4+quad), gates q=0..3 in the 4 acc regs. 8 waves x 4 row-tiles.
__global__ __launch_bounds__(512, 1) void lstm_scan(
    const void* __restrict__ x0_, const void* __restrict__ len0,
    const void* __restrict__ sub_ta, const void* __restrict__ sub_tf,
    const void* __restrict__ x1_, const void* __restrict__ len1,
    const void* __restrict__ sub_an,
    const void* __restrict__ x2_, const void* __restrict__ len2,
    const void* __restrict__ sub_fa,
    const void* __restrict__ Wih, const void* __restrict__ Whh,
    const void* __restrict__ bih, const void* __restrict__ bhh,
    float* __restrict__ ws)
{
  const int e      = blockIdx.y;
  const int s0     = blockIdx.x * M;
  const int tid    = threadIdx.x;
  const int lane   = tid & 63;
  const int w      = tid >> 6;     // wave 0..7, owns h-cols [16w,16w+16)
  const int lo     = lane & 15;    // = seq (B/D col)
  const int quad   = lane >> 4;

  // ---- in-block dtype detection (uniform scalar loop; block (0,0) publishes for dists)
  int fbf, f64;
  {
    const unsigned int* wp = (const unsigned int*)Whh;
    int cnt = 0;
    for (int i = 0; i < 64; ++i) {
      unsigned int lo16 = wp[i] & 0xFFFFu;
      int ex = (int)((lo16 >> 7) & 0xFFu);
      cnt += (ex >= 100 && ex <= 130);
    }
    fbf = (cnt >= 40);
    const unsigned int* l = (const unsigned int*)len0;
    f64 = ((l[1] | l[3] | l[5] | l[7]) == 0u);
    if (blockIdx.x == 0 && blockIdx.y == 0 && tid == 0) {
      int* fo = (int*)(ws + WS_FLAGS); fo[0] = fbf; fo[1] = f64;
    }
  }

  const void* xin  = (e==0) ? x0_ : (e==1 ? x1_ : x2_);
  const void* lenp = (e==0) ? len0 : (e==1 ? len1 : len2);

  // h^T ping-pong: hb[buf][kt 4][kq 4][seq 16][jj 8] = h[seq][k=kt*32+kq*8+jj]  (f16)
  __shared__ __align__(16) _Float16 hb[2][4][4][16][8];       // 8 KB
  // x chunks: 64 steps x 16 seqs, double-buffered, +1 col pad kills bank conflicts
  __shared__ __align__(16) float2 xc[2][16][65];              // 16.6 KB

  for (int i = tid; i < 2048; i += 512) ((unsigned int*)hb)[i] = 0u;  // zero both h bufs

  // ---- stage x chunk 0 to LDS; issue raw loads for chunk 1 into registers
  #pragma unroll
  for (int k2 = 0; k2 < 2; ++k2) {
    int i = tid + k2*512, seq = i >> 6, tl = i & 63, sg = s0 + seq;
    float2 v = make_float2(0.f, 0.f);
    if (sg < BB) {
      size_t base = ((size_t)sg*T + tl) * DX;
      v = make_float2(loadF(xin, base + 0, fbf), loadF(xin, base + 1, fbf));
    }
    xc[0][seq][tl] = v;
  }
  uint2 Rx[2];
  #pragma unroll
  for (int k2 = 0; k2 < 2; ++k2) {
    int i = tid + k2*512, seq = i >> 6, tl = i & 63, sg = s0 + seq;
    uint2 r = make_uint2(0u, 0u);
    if (sg < BB) {
      size_t base = ((size_t)sg*T + (64 + tl)) * DX;
      if (fbf) r.x = *(const unsigned int*)((const unsigned short*)xin + base);
      else { const unsigned int* pu = (const unsigned int*)xin; r.x = pu[base]; r.y = pu[base+1]; }
    }
    Rx[k2] = r;
  }

  // ---- A-fragments: static weights, 4 row-tiles per wave, pre-scaled
  // lane holds A[row=lo][k=kt*32+quad*8+j]; row lo -> hcol_local=lo>>2, gate=lo&3
  half8 Af[4][4];
  {
    const int qw = lo & 3, hcl = lo >> 2;
    const float sc = (qw == 2) ? LOG2E2 : LOG2E;
    #pragma unroll
    for (int rt = 0; rt < 4; ++rt) {
      const size_t row = (size_t)(qw*128 + (w*4 + rt)*4 + hcl) * H;
      #pragma unroll
      for (int kt = 0; kt < 4; ++kt)
        #pragma unroll
        for (int j = 0; j < 8; ++j)
          Af[rt][kt][j] = (_Float16)(sc * loadF(Whh, row + kt*32 + quad*8 + j, fbf));
    }
  }
  // ---- per-lane x-weights and bias for my 4 cells (seq=lo, hcol=(w*4+rt)*4+quad)
  float wx0[4][4], wx1[4][4], bbq[4][4];
  #pragma unroll
  for (int rt = 0; rt < 4; ++rt) {
    const int hcc = (w*4 + rt)*4 + quad;
    #pragma unroll
    for (int q = 0; q < 4; ++q) {
      const float sc = (q == 2) ? LOG2E2 : LOG2E;
      const int g = q*128 + hcc;
      wx0[rt][q] = sc * loadF(Wih, (size_t)g*2 + 0, fbf);
      wx1[rt][q] = sc * loadF(Wih, (size_t)g*2 + 1, fbf);
      bbq[rt][q] = sc * (loadF(bih, g, fbf) + loadF(bhh, g, fbf));
    }
  }
  // ---- per-thread watcher (off kept in a register; snapshots write global directly)
  int myt = -2, mym = 0, myoff = 0;
  if (e == 0) {
    if (tid < M*21) {
      int m = tid / 21, j = tid - m*21, sg = s0 + m;
      mym = m;
      if (sg < BB) {
        if (j == 0)       { myt = clampT(loadI(lenp, sg, f64));            myoff = WS_TEMB + sg*H; }
        else if (j <= 10) { int k = sg*10 + (j-1);  myt = clampT(loadI(sub_ta, k, f64)); myoff = WS_TA + k*H; }
        else              { int k = sg*10 + (j-11); myt = clampT(loadI(sub_tf, k, f64)); myoff = WS_TF + k*H; }
      }
    }
  } else {
    if (tid < M*11) {
      int m = tid / 11, j = tid - m*11, sg = s0 + m;
      mym = m;
      if (sg < BB) {
        if (j == 0) { myt = clampT(loadI(lenp, sg, f64)); myoff = (e==1 ? WS_AEMB : WS_FEMB) + sg*H; }
        else {
          int k = sg*10 + (j-1);
          if (e == 1) { myt = clampT(loadI(sub_an, k, f64)); myoff = WS_AN + k*H; }
          else        { myt = clampT(loadI(sub_fa, k, f64)); myoff = WS_FA + k*H; }
        }
      }
    }
  }

  // ---- hoisted addresses
  const _Float16* hb0 = &hb[0][0][0][0][0];
  const _Float16* hb1 = &hb[1][0][0][0][0];
  const _Float16* rdb[2] = { hb0, hb1 };
  // B-frag read: lane -> hb[.][kt][quad][lo][0..7]
  const int rdoff = quad*128 + lo*8;
  // h writes: cell hcol hcc -> halves offset (hcc>>5)*512 + ((hcc>>3)&3)*128 + lo*8 + (hcc&7)
  _Float16* wrp[2][4];
  #pragma unroll
  for (int rt = 0; rt < 4; ++rt) {
    const int hcc = (w*4 + rt)*4 + quad;
    const int offh = (hcc>>5)*512 + ((hcc>>3)&3)*128 + lo*8 + (hcc&7);
    wrp[0][rt] = (_Float16*)hb0 + offh;
    wrp[1][rt] = (_Float16*)hb1 + offh;
  }
  const int c0 = 2*lane;
  const int snap_kb = (c0>>5)*512 + ((c0>>3)&3)*128 + (c0&7);   // + m*8

  // ---- ballot-cooperative snapshot of step tq (h(tq+1) in buffer rp) -> GLOBAL ws
  auto snap = [&](int tq, int rp) {
    unsigned long long mask = __ballot(myt == tq);
    if (mask) {
      const _Float16* sb = rdb[rp];
      do {
        int src = __ffsll((unsigned long long)mask) - 1;
        mask &= mask - 1;
        int m   = __shfl(mym, src);
        int off = __shfl(myoff, src);
        unsigned int pk = *(const unsigned int*)(sb + snap_kb + m*8);
        float2 v;
        v.x = (float)__builtin_bit_cast(_Float16, (unsigned short)(pk & 0xFFFFu));
        v.y = (float)__builtin_bit_cast(_Float16, (unsigned short)(pk >> 16));
        *(float2*)(ws + off + c0) = v;
      } while (mask);
    }
  };

  __syncthreads();

  // ---- persistent accumulators: G[rt][q] enters each step holding px(t)[gate q]
  f32x4 G[4];
  float cs[4] = {0.f, 0.f, 0.f, 0.f};
  {
    float2 xv0 = xc[0][lo][0];
    #pragma unroll
    for (int rt = 0; rt < 4; ++rt)
      #pragma unroll
      for (int q = 0; q < 4; ++q)
        G[rt][q] = bbq[rt][q] + wx0[rt][q]*xv0.x + wx1[rt][q]*xv0.y;
  }

  // one LSTM step: B = h^T(t) from buffer rp; writes h(t+1) into wp.
  // last==true on the final step of each 64-step chunk (x(t+1) not in LDS yet).
  auto step = [&](int rp, int wp, int t, bool last) {
    const _Float16* rb = rdb[rp] + rdoff;
    half8 Bh[4];
    #pragma unroll
    for (int kt = 0; kt < 4; ++kt)
      Bh[kt] = *(const half8*)(rb + kt*512);
    float2 xn;
    if (!last) xn = xc[(t>>6)&1][lo][(t+1)&63];

    #pragma unroll
    for (int kt = 0; kt < 4; ++kt)      // 4 indep acc chains of depth 4
      #pragma unroll
      for (int rt = 0; rt < 4; ++rt)
        G[rt] = __builtin_amdgcn_mfma_f32_16x16x32_f16(Af[rt][kt], Bh[kt], G[rt], 0, 0, 0);

    // ---- MFMA-shadow work (independent of MFMA results)
    float pxn[4][4];
    if (!last) {
      #pragma unroll
      for (int rt = 0; rt < 4; ++rt)
        #pragma unroll
        for (int q = 0; q < 4; ++q)
          pxn[rt][q] = bbq[rt][q] + wx0[rt][q]*xn.x + wx1[rt][q]*xn.y;
    }
    snap(t-1, rp);

    // ---- activations: 4 cells (seq=lo, hcol=(w*4+rt)*4+quad)
    #pragma unroll
    for (int rt = 0; rt < 4; ++rt) {
      float sf = sigmY(G[rt][1]);
      float si = sigmY(G[rt][0]);
      float tg = tanhY(G[rt][2]);
      float ig = (si * tg) * LOG2E2;
      cs[rt] = sf*cs[rt] + ig;
      float tc = tanhY(cs[rt]);
      float so = sigmY(G[rt][3]);
      *wrp[wp][rt] = (_Float16)(so * tc);
    }
    if (!last) {
      #pragma unroll
      for (int rt = 0; rt < 4; ++rt)
        #pragma unroll
        for (int q = 0; q < 4; ++q)
          G[rt][q] = pxn[rt][q];
    }
    __syncthreads();
  };

  #pragma unroll 1
  for (int t = 0; t < T; t += 2) {
    step(0, 1, t, false);
    step(1, 0, t+1, (t & 63) == 62);
    if ((t & 63) == 62 && t + 2 < T) {
      const int tb1 = (t >> 6) + 1;          // chunk starting at step t+2
      // drain chunk-tb1 loads, publish to LDS
      #pragma unroll
      for (int k2 = 0; k2 < 2; ++k2) {
        int i = tid + k2*512, seq = i >> 6, tl = i & 63;
        float2 v;
        if (fbf) v = make_float2(bf2f((unsigned short)(Rx[k2].x & 0xFFFFu)),
                                 bf2f((unsigned short)(Rx[k2].x >> 16)));
        else     v = make_float2(__builtin_bit_cast(float, Rx[k2].x),
                                 __builtin_bit_cast(float, Rx[k2].y));
        xc[tb1 & 1][seq][tl] = v;
      }
      // issue loads for chunk tb1+1
      if (tb1 + 1 < NCH) {
        #pragma unroll
        for (int k2 = 0; k2 < 2; ++k2) {
          int i = tid + k2*512, seq = i >> 6, tl = i & 63, sg = s0 + seq;
          uint2 r = make_uint2(0u, 0u);
          if (sg < BB) {
            size_t base = ((size_t)sg*T + ((tb1 + 1)*64 + tl)) * DX;
            if (fbf) r.x = *(const unsigned int*)((const unsigned short*)xin + base);
            else { const unsigned int* pu = (const unsigned int*)xin; r.x = pu[base]; r.y = pu[base+1]; }
          }
          Rx[k2] = r;
        }
      }
      __syncthreads();
      // re-arm px/G for step t+2 from the fresh chunk
      float2 xv = xc[tb1 & 1][lo][0];
      #pragma unroll
      for (int rt = 0; rt < 4; ++rt)
        #pragma unroll
        for (int q = 0; q < 4; ++q)
          G[rt][q] = bbq[rt][q] + wx0[rt][q]*xv.x + wx1[rt][q]*xv.y;
    }
  }

  // final snapshot: outputs of step T-1 live in buffer 0
  snap(T-1, 0);
}

__global__ void dists(const float* __restrict__ ws, void* __restrict__ outv) {
  const int fbf = ((const int*)(ws + WS_FLAGS))[0];
  const int gtid = blockIdx.x*256 + threadIdx.x;
  const int widx = gtid >> 6, lane = gtid & 63;
  const float *pa, *pb;
  if (widx < 220)       { pa = ws + WS_TEMB + (size_t)widx*H;        pb = ws + WS_AEMB + (size_t)widx*H; }
  else if (widx < 440)  { int b = widx-220;  pa = ws + WS_TEMB + (size_t)b*H; pb = ws + WS_FEMB + (size_t)b*H; }
  else if (widx < 2640) { int k = widx-440;  pa = ws + WS_TA + (size_t)k*H;   pb = ws + WS_AN + (size_t)k*H; }
  else                  { int k = widx-2640; pa = ws + WS_TF + (size_t)k*H;   pb = ws + WS_FA + (size_t)k*H; }
  float d0 = pa[lane]    - pb[lane];
  float d1 = pa[lane+64] - pb[lane+64];
  float s  = scrub(d0*d0 + d1*d1);
  #pragma unroll
  for (int off = 32; off > 0; off >>= 1) s += __shfl_down(s, off, 64);
  if (lane == 0) {
    float r = __expf(-sqrtf(s));
    if (fbf) ((unsigned short*)outv)[widx] = f2bf(r);
    else     ((float*)outv)[widx] = r;
  }
}

extern "C" void kernel_launch(void* const* d_in, const int* in_sizes, int n_in,
                              void* d_out, int out_size, void* d_ws, size_t ws_size,
                              hipStream_t stream) {
  float* ws = (float*)d_ws;
  hipLaunchKernelGGL(lstm_scan, dim3(NBLK, 3), dim3(512), 0, stream,
                     d_in[0], d_in[1], d_in[2], d_in[3],
                     d_in[4], d_in[5], d_in[6],
                     d_in[7], d_in[8], d_in[9],
                     d_in[10], d_in[11], d_in[12], d_in[13], ws);
  hipLaunchKernelGGL(dists, dim3(4840*64/256), dim3(256), 0, stream, ws, d_out);
}

// Round 6
// 353.338 us; speedup vs baseline: 1.5448x; 1.5448x over previous
//
#include <hip/hip_runtime.h>

#define H    128
#define T    512
#define DX   4
#define BB   220
#define SAMP 10
#define NS   (BB*SAMP)
#define M    4        // sequences per block (220 = 55*4, no tail)
#define NBLK 55       // 220/4
#define MAXSLOT 84    // max watcher slots per block (e==0: M*21)

typedef _Float16 half8 __attribute__((ext_vector_type(8)));
typedef float    f32x4 __attribute__((ext_vector_type(4)));

// workspace layout (fp32 elements)
#define WS_TEMB 0
#define WS_AEMB (WS_TEMB + BB*H)
#define WS_FEMB (WS_AEMB + BB*H)
#define WS_TA   (WS_FEMB + BB*H)
#define WS_TF   (WS_TA + NS*H)
#define WS_AN   (WS_TF + NS*H)
#define WS_FA   (WS_AN + NS*H)
#define WS_FLAGS (WS_FA + NS*H)   // 2 ints: [0]=floats-are-bf16, [1]=ints-are-int64

#define LOG2E  1.442695041f
#define LOG2E2 2.885390082f

__device__ static inline float bf2f(unsigned short u) {
  unsigned int i = ((unsigned int)u) << 16;
  return __builtin_bit_cast(float, i);
}
__device__ static inline unsigned short f2bf(float f) {
  unsigned int i = __builtin_bit_cast(unsigned int, f);
  i += 0x7fffu + ((i >> 16) & 1u);
  return (unsigned short)(i >> 16);
}
__device__ static inline float loadF(const void* p, size_t i, int isbf) {
  return isbf ? bf2f(((const unsigned short*)p)[i]) : ((const float*)p)[i];
}
__device__ static inline int loadI(const void* p, int i, int is64) {
  return is64 ? (int)((const unsigned int*)p)[2*(size_t)i] : ((const int*)p)[i];
}
__device__ static inline float frcp(float x) { return __builtin_amdgcn_rcpf(x); }
__device__ static inline float ex2(float x)  { return __builtin_amdgcn_exp2f(x); }
// args pre-scaled by log2e (sigm) / 2*log2e (tanh)
__device__ static inline float sigmY(float y)  { return frcp(1.f + ex2(-y)); }
__device__ static inline float tanhY(float y)  { return 1.f - 2.f*frcp(1.f + ex2(y)); }
__device__ static inline float scrub(float x) { return (x == x) ? x : 0.f; }
__device__ static inline int clampT(int v) { v = v - 1; if (v < 0) v = 0; if (v > T-1) v = T-1; return v; }

__global__ __launch_bounds__(512, 2) void lstm_scan(
    const void* __restrict__ x0_, const void* __restrict__ len0,
    const void* __restrict__ sub_ta, const void* __restrict__ sub_tf,
    const void* __restrict__ x1_, const void* __restrict__ len1,
    const void* __restrict__ sub_an,
    const void* __restrict__ x2_, const void* __restrict__ len2,
    const void* __restrict__ sub_fa,
    const void* __restrict__ Wih, const void* __restrict__ Whh,
    const void* __restrict__ bih, const void* __restrict__ bhh,
    float* __restrict__ ws)
{
  const int e      = blockIdx.y;
  const int s0     = blockIdx.x * M;
  const int tid    = threadIdx.x;
  const int lane   = tid & 63;
  const int w      = tid >> 6;     // wave 0..7, owns h-cols [16w,16w+16)
  const int lo     = lane & 15;
  const int quad   = lane >> 4;    // elementwise: my seq

  // ---- in-block dtype detection (uniform scalar loop; block (0,0) publishes for dists)
  int fbf, f64;
  {
    const unsigned int* wp = (const unsigned int*)Whh;
    int cnt = 0;
    for (int i = 0; i < 64; ++i) {
      unsigned int lo16 = wp[i] & 0xFFFFu;
      int ex = (int)((lo16 >> 7) & 0xFFu);
      cnt += (ex >= 100 && ex <= 130);
    }
    fbf = (cnt >= 40);
    const unsigned int* l = (const unsigned int*)len0;
    f64 = ((l[1] | l[3] | l[5] | l[7]) == 0u);
    if (blockIdx.x == 0 && blockIdx.y == 0 && tid == 0) {
      int* fo = (int*)(ws + WS_FLAGS); fo[0] = fbf; fo[1] = f64;
    }
  }

  const void* xin  = (e==0) ? x0_ : (e==1 ? x1_ : x2_);
  const void* lenp = (e==0) ? len0 : (e==1 ? len1 : len2);

  // h'(t) in MFMA-fragment-major order: [buf][ktile][chunk][8 halves]
  // afr[.][kt][chunk][j] = h[seq = chunk&3][k = kt*32 + (chunk>>2)*8 + j]
  __shared__ __align__(16) _Float16 afr[2][4][16][8];
  __shared__ __align__(16) float2 xbf[M][T+2];            // x pairs, stride T+2
  __shared__ __align__(16) _Float16 sbuf[MAXSLOT][H];     // watcher snapshots (f16)
  __shared__ int slot_off[MAXSLOT];                       // ws offset per slot

  ((unsigned int*)afr)[tid] = 0u;                         // zero both h buffers
  // ---- stage x[:, :, 0:2] to LDS as f32 pairs
  for (int i = tid; i < M*T; i += 512) {
    int m = i >> 9, t = i & (T-1);
    size_t base = ((size_t)(s0+m)*T + t) * DX;
    xbf[m][t] = make_float2(loadF(xin, base + 0, fbf), loadF(xin, base + 1, fbf));
  }
  // ---- weight B-fragments: W_hh only, K=128; pre-scaled (i,f,o: log2e; g: 2*log2e)
  half8 Bf[4][4];
  const int col = w*16 + lo;
  #pragma unroll
  for (int q = 0; q < 4; ++q) {
    const float sc = (q == 2) ? LOG2E2 : LOG2E;
    const int g = q*128 + col;
    #pragma unroll
    for (int kt = 0; kt < 4; ++kt) {
      #pragma unroll
      for (int j = 0; j < 8; ++j) {
        const int k = kt*32 + quad*8 + j;
        Bf[q][kt][j] = (_Float16)(sc * loadF(Whh, (size_t)g*H + k, fbf));
      }
    }
  }
  // ---- per-lane x-weights and bias for my cell (seq=quad, col)
  float wx0[4], wx1[4], bb[4];
  #pragma unroll
  for (int q = 0; q < 4; ++q) {
    const float sc = (q == 2) ? LOG2E2 : LOG2E;
    const int g = q*128 + col;
    wx0[q] = sc * loadF(Wih, (size_t)g*2 + 0, fbf);
    wx1[q] = sc * loadF(Wih, (size_t)g*2 + 1, fbf);
    bb[q]  = sc * (loadF(bih, g, fbf) + loadF(bhh, g, fbf));
  }
  // ---- per-thread watcher slot (slot id == tid; max 84 < 512)
  const int nslots = (e == 0) ? M*21 : M*11;
  int myt = -2, mym = 0;     // -2: never matches t-1 (>= -1)
  if (e == 0) {
    if (tid < M*21) {
      int m = tid / 21, j = tid - m*21, sg = s0 + m;
      mym = m;
      int off;
      if (j == 0)       { myt = clampT(loadI(lenp, sg, f64));            off = WS_TEMB + sg*H; }
      else if (j <= 10) { int k = sg*10 + (j-1);  myt = clampT(loadI(sub_ta, k, f64)); off = WS_TA + k*H; }
      else              { int k = sg*10 + (j-11); myt = clampT(loadI(sub_tf, k, f64)); off = WS_TF + k*H; }
      slot_off[tid] = off;
    }
  } else {
    if (tid < M*11) {
      int m = tid / 11, j = tid - m*11, sg = s0 + m;
      mym = m;
      int off;
      if (j == 0) { myt = clampT(loadI(lenp, sg, f64)); off = (e==1 ? WS_AEMB : WS_FEMB) + sg*H; }
      else {
        int k = sg*10 + (j-1);
        if (e == 1) { myt = clampT(loadI(sub_an, k, f64)); off = WS_AN + k*H; }
        else        { myt = clampT(loadI(sub_fa, k, f64)); off = WS_FA + k*H; }
      }
      slot_off[tid] = off;
    }
  }
  __syncthreads();

  float cs = 0.f;                 // c-state in scaled domain: cs = c * 2log2e
  // ---- hoisted loop-invariant addresses
  // A-row remap: A[row][k] = h[row>>2][k]  (rows 0-3 seq0, 4-7 seq1, ...)
  // => lane reads chunk quad*4 + (lo>>2); C rows 4*quad+r are ALL seq quad => R[q]=G[q][0]
  const int rdchunk = quad*4 + (lo >> 2);
  const _Float16* rdb[2] = { &afr[0][0][rdchunk][0], &afr[1][0][rdchunk][0] };
  const _Float16* sbb[2] = { &afr[0][0][0][0], &afr[1][0][0][0] };
  const int wrkt    = w >> 1;
  const int wrchunk = ((w & 1)*2 + (lo >> 3))*4 + quad;
  const int wrj     = lo & 7;
  _Float16* wrb[2] = { &afr[0][wrkt][wrchunk][wrj], &afr[1][wrkt][wrchunk][wrj] };
  const float2* xrow = &xbf[quad][0];
  const int c0 = 2*lane;
  const int snap_base = (c0 >> 5)*128 + ((c0 >> 3) & 3)*32 + (c0 & 7);  // + m*8

  // ---- ballot-cooperative watcher snapshot of step tq (h(tq+1) lives in buffer rp)
  auto snap = [&](int tq, int rp) {
    unsigned long long mask = __ballot(myt == tq);
    if (mask) {
      const _Float16* sb = sbb[rp];
      do {
        int src = __ffsll((unsigned long long)mask) - 1;
        mask &= mask - 1;
        int m    = __shfl(mym, src);
        int slot = w*64 + src;
        unsigned int pk = *(const unsigned int*)(sb + snap_base + m*8);
        *(unsigned int*)&sbuf[slot][c0] = pk;
      } while (mask);
    }
  };

  // ---- persistent accumulators: comp 0 enters each step holding bias+x-projection;
  // comps 1-3 accumulate a bounded random walk of unused garbage (never read,
  // never reset -> saves 32 init-movs + 4 extract-adds per step).
  f32x4 G[4];
  float2 xn;
  {
    float2 xv0 = xrow[0];
    #pragma unroll
    for (int q = 0; q < 4; ++q)
      G[q] = (f32x4){ bb[q] + wx0[q]*xv0.x + wx1[q]*xv0.y, 0.f, 0.f, 0.f };
    xn = xrow[1];
  }

  // one LSTM step: read h' from buffer rp, write h(t+1) into buffer wp
  auto step = [&](int rp, int wp, int t) {
    const _Float16* rb = rdb[rp];
    half8 A[4];
    #pragma unroll
    for (int kt = 0; kt < 4; ++kt)
      A[kt] = *(const half8*)(rb + kt*128);

    // 16 MFMA: 4 independent chains of depth 4. setprio(1) makes the first wave
    // into the cluster win the pipe and finish first -> its activations overlap
    // the other wave's MFMA drain (cross-wave phase-split).
    __builtin_amdgcn_s_setprio(1);
    #pragma unroll
    for (int kt = 0; kt < 4; ++kt)
      #pragma unroll
      for (int q = 0; q < 4; ++q)
        G[q] = __builtin_amdgcn_mfma_f32_16x16x32_f16(A[kt], Bf[q][kt], G[q], 0, 0, 0);
    __builtin_amdgcn_s_setprio(0);

    // ---- MFMA-shadow work (independent of MFMA results)
    float pxn[4];
    #pragma unroll
    for (int q = 0; q < 4; ++q)
      pxn[q] = bb[q] + wx0[q]*xn.x + wx1[q]*xn.y;
    xn = xrow[t+2];            // [T+2] row padding keeps this in-bounds
    snap(t-1, rp);

    // ---- activations (read G[q][0] only)
    float sf = sigmY(G[1][0]);
    float si = sigmY(G[0][0]);
    float tg = tanhY(G[2][0]);
    float ig = (si * tg) * LOG2E2;          // off-chain product, pre-scaled
    cs = sf*cs + ig;                         // serial chain: fma only
    float tc = tanhY(cs);                    // no mul on chain
    float so = sigmY(G[3][0]);               // hides under the cs->tanh chain
    *wrb[wp] = (_Float16)(so * tc);
    // re-arm comp 0 with next step's x-projection (after acts read it)
    #pragma unroll
    for (int q = 0; q < 4; ++q)
      G[q][0] = pxn[q];
    __syncthreads();
  };

  #pragma unroll 1
  for (int t = 0; t < T; t += 2) {
    step(0, 1, t);
    step(1, 0, t+1);
  }

  // final snapshot: outputs of step T-1 live in buffer 0
  snap(T-1, 0);

  __syncthreads();
  // ---- bulk snapshot write-out: slots * 64 dwords, coalesced
  for (int i = tid; i < nslots*64; i += 512) {
    int slot = i >> 6, c2 = i & 63;
    unsigned int pk = *(const unsigned int*)&sbuf[slot][2*c2];
    float2 v;
    v.x = (float)__builtin_bit_cast(_Float16, (unsigned short)(pk & 0xFFFFu));
    v.y = (float)__builtin_bit_cast(_Float16, (unsigned short)(pk >> 16));
    *(float2*)(ws + slot_off[slot] + 2*c2) = v;
  }
}

__global__ void dists(const float* __restrict__ ws, void* __restrict__ outv) {
  const int fbf = ((const int*)(ws + WS_FLAGS))[0];
  const int gtid = blockIdx.x*256 + threadIdx.x;
  const int widx = gtid >> 6, lane = gtid & 63;
  const float *pa, *pb;
  if (widx < 220)       { pa = ws + WS_TEMB + (size_t)widx*H;        pb = ws + WS_AEMB + (size_t)widx*H; }
  else if (widx < 440)  { int b = widx-220;  pa = ws + WS_TEMB + (size_t)b*H; pb = ws + WS_FEMB + (size_t)b*H; }
  else if (widx < 2640) { int k = widx-440;  pa = ws + WS_TA + (size_t)k*H;   pb = ws + WS_AN + (size_t)k*H; }
  else                  { int k = widx-2640; pa = ws + WS_TF + (size_t)k*H;   pb = ws + WS_FA + (size_t)k*H; }
  float d0 = pa[lane]    - pb[lane];
  float d1 = pa[lane+64] - pb[lane+64];
  float s  = scrub(d0*d0 + d1*d1);
  #pragma unroll
  for (int off = 32; off > 0; off >>= 1) s += __shfl_down(s, off, 64);
  if (lane == 0) {
    float r = __expf(-sqrtf(s));
    if (fbf) ((unsigned short*)outv)[widx] = f2bf(r);
    else     ((float*)outv)[widx] = r;
  }
}

extern "C" void kernel_launch(void* const* d_in, const int* in_sizes, int n_in,
                              void* d_out, int out_size, void* d_ws, size_t ws_size,
                              hipStream_t stream) {
  float* ws = (float*)d_ws;
  hipLaunchKernelGGL(lstm_scan, dim3(NBLK, 3), dim3(512), 0, stream,
                     d_in[0], d_in[1], d_in[2], d_in[3],
                     d_in[4], d_in[5], d_in[6],
                     d_in[7], d_in[8], d_in[9],
                     d_in[10], d_in[11], d_in[12], d_in[13], ws);
  hipLaunchKernelGGL(dists, dim3(4840*64/256), dim3(256), 0, stream, ws, d_out);
}